// Round 13
// baseline (253.743 us; speedup 1.0000x reference)
//
#include <hip/hip_runtime.h>
#include <hip/hip_bf16.h>

#define NPAIR 4096
#define DIM   768            // fp8: 768 bytes per row
#define N2    8192
#define BM    128            // 4 waves x 32 rows
#define CT    64             // cols per B tile
#define NCT   8              // col-tiles per block (512-col strip)
#define KT    48             // K granules of 16B (768/16)
#define NBI   (N2 / BM)      // 64
#define NSTRIP (N2 / (CT * NCT))  // 16

constexpr float INV_T = 1.0f / 0.07f;  // also the fixed softmax max M

typedef float f32x16 __attribute__((ext_vector_type(16)));
#define AS1 __attribute__((address_space(1)))
#define AS3 __attribute__((address_space(3)))

// ---------------- normalize: one wave per row, fp32 in -> fp8 e4m3 out ------
__global__ void knorm(const float* __restrict__ z1, const float* __restrict__ z2,
                      unsigned char* __restrict__ zq) {
    const int row  = blockIdx.x * 4 + (threadIdx.x >> 6);
    const int lane = threadIdx.x & 63;
    const float* src = (row < NPAIR) ? (z1 + (size_t)row * DIM)
                                     : (z2 + (size_t)(row - NPAIR) * DIM);
    float4 v[3];
    float ss = 0.f;
#pragma unroll
    for (int i = 0; i < 3; ++i) {
        v[i] = reinterpret_cast<const float4*>(src)[lane + 64 * i];
        ss += v[i].x * v[i].x + v[i].y * v[i].y + v[i].z * v[i].z + v[i].w * v[i].w;
    }
#pragma unroll
    for (int off = 32; off; off >>= 1) ss += __shfl_xor(ss, off);
    const float scale = 1.0f / fmaxf(sqrtf(ss), 1e-12f);
    unsigned int* dst = reinterpret_cast<unsigned int*>(zq + (size_t)row * DIM);
#pragma unroll
    for (int i = 0; i < 3; ++i) {
        unsigned int u = 0;
        u = __builtin_amdgcn_cvt_pk_fp8_f32(v[i].x * scale, v[i].y * scale, u, false);
        u = __builtin_amdgcn_cvt_pk_fp8_f32(v[i].z * scale, v[i].w * scale, u, true);
        dst[lane + 64 * i] = u;
    }
}

// ---------------- positive-pair dots from fp8 (consistent with klse) --------
__global__ void kpos(const unsigned char* __restrict__ zq, float* __restrict__ pos) {
    const int pair = blockIdx.x * 4 + (threadIdx.x >> 6);
    const int lane = threadIdx.x & 63;
    const unsigned int* a = reinterpret_cast<const unsigned int*>(zq + (size_t)pair * DIM);
    const unsigned int* b = reinterpret_cast<const unsigned int*>(zq + (size_t)(pair + NPAIR) * DIM);
    float s = 0.f;
#pragma unroll
    for (int i = 0; i < 3; ++i) {
        const unsigned int ua = a[lane + 64 * i];
        const unsigned int ub = b[lane + 64 * i];
        s += __builtin_amdgcn_cvt_f32_fp8(ua, 0) * __builtin_amdgcn_cvt_f32_fp8(ub, 0);
        s += __builtin_amdgcn_cvt_f32_fp8(ua, 1) * __builtin_amdgcn_cvt_f32_fp8(ub, 1);
        s += __builtin_amdgcn_cvt_f32_fp8(ua, 2) * __builtin_amdgcn_cvt_f32_fp8(ub, 2);
        s += __builtin_amdgcn_cvt_f32_fp8(ua, 3) * __builtin_amdgcn_cvt_f32_fp8(ub, 3);
    }
#pragma unroll
    for (int off = 32; off; off >>= 1) s += __shfl_xor(s, off);
    if (lane == 0) pos[pair] = s * INV_T;
}

// ---------------- main: A-in-registers, full-K B tiles ----------------------
// Wave = 32 rows; A sub-tile (32 x 768 fp8) lives in 96 VGPRs for the whole
// kernel. Per col-tile: stage B (64 cols x full K = 48KB) once, then a
// 48-step K-loop of {2 ds_read_b64 + 2 MFMA} with NO barriers. Only 2
// barriers per col-tile (8 per block vs 96 in R11). Per-lane exp-accumulate;
// one butterfly + atomics per wave at block end.
__global__ __launch_bounds__(256, 3) void klse(const unsigned char* __restrict__ zq,
                                               float* __restrict__ rowsum) {
    __shared__ __align__(16) unsigned char Bs[CT * DIM];   // 48 KB
    const int tid  = threadIdx.x;
    const int wave = tid >> 6;
    const int lane = tid & 63;
    const int hi = lane >> 5, rlo = lane & 31;
    const int rb = blockIdx.x * BM;
    const int c00 = blockIdx.y * (CT * NCT);
    const int sw = rlo & 7;

    // A: 32 rows x K=768 for this wave, in registers (96 VGPR)
    long areg[KT];
    {
        const unsigned char* ap = zq + (size_t)(rb + wave * 32 + rlo) * DIM + hi * 8;
#pragma unroll
        for (int t = 0; t < KT; ++t)
            areg[t] = *reinterpret_cast<const long*>(ap + t * 16);
    }

    float rowacc[16];
#pragma unroll
    for (int r = 0; r < 16; ++r) rowacc[r] = 0.f;

    // stage B col-tile ct: 3072 granules of 16B, 12 per thread; source
    // XOR-swizzled (granule ks <-> ks ^ (col&7)), LDS linear [col][768B]
    auto stage = [&](int ct) {
        const int c0 = c00 + ct * CT;
#pragma unroll
        for (int i = 0; i < 12; ++i) {
            const int g = i * 256 + tid;
            const int col = g / KT, ks = g - col * KT;
            const int kk = (ks ^ (col & 7)) << 4;
            __builtin_amdgcn_global_load_lds(
                (const AS1 unsigned int*)(zq + (size_t)(c0 + col) * DIM + kk),
                (AS3 unsigned int*)(Bs + g * 16), 16, 0, 0);
        }
    };

    stage(0);
    asm volatile("s_waitcnt vmcnt(0)" ::: "memory");
    __builtin_amdgcn_s_barrier();

    for (int ct = 0; ct < NCT; ++ct) {
        f32x16 acc0 = {}, acc1 = {};
#pragma unroll
        for (int t = 0; t < KT; ++t) {
            const int so = ((t ^ sw) << 4) + (hi << 3);   // swizzled 8B offset
            long b0 = *reinterpret_cast<const long*>(&Bs[rlo * DIM + so]);
            long b1 = *reinterpret_cast<const long*>(&Bs[(rlo + 32) * DIM + so]);
            acc0 = __builtin_amdgcn_mfma_f32_32x32x16_fp8_fp8(areg[t], b0, acc0, 0, 0, 0);
            acc1 = __builtin_amdgcn_mfma_f32_32x32x16_fp8_fp8(areg[t], b1, acc1, 0, 0, 0);
        }
        __builtin_amdgcn_s_barrier();          // all waves done reading Bs
        if (ct + 1 < NCT) stage(ct + 1);       // issue next tile's loads

        // epilogue on registers while the loads fly
        const int c0 = c00 + ct * CT;
        const int row0 = rb + wave * 32 + 4 * hi;
        const int colg = c0 + rlo;
        const bool on_diag = (c0 + CT > rb) && (c0 < rb + BM);
#pragma unroll
        for (int r = 0; r < 16; ++r) {
            float e0 = __expf((acc0[r] - 1.0f) * INV_T);
            float e1 = __expf((acc1[r] - 1.0f) * INV_T);
            if (on_diag) {
                const int rg = row0 + (r & 3) + 8 * (r >> 2);
                if (rg == colg)      e0 = 0.f;
                if (rg == colg + 32) e1 = 0.f;
            }
            rowacc[r] += e0 + e1;
        }
        if (ct + 1 < NCT) {
            asm volatile("s_waitcnt vmcnt(0)" ::: "memory");  // next tile landed
            __builtin_amdgcn_s_barrier();
        }
    }

    // block end: butterfly over the 32 col-lanes, one atomic per row
#pragma unroll
    for (int r = 0; r < 16; ++r) {
#pragma unroll
        for (int m = 1; m < 32; m <<= 1)
            rowacc[r] += __shfl_xor(rowacc[r], m);
    }
    if (rlo == 0) {
        const int row0 = rb + wave * 32 + 4 * hi;
#pragma unroll
        for (int r = 0; r < 16; ++r)
            atomicAdd(&rowsum[row0 + (r & 3) + 8 * (r >> 2)], rowacc[r]);
    }
}

// ---------------- final: loss = mean(M + log S_i - pos) ---------------------
__global__ void kfinal(const float* __restrict__ rowsum, const float* __restrict__ pos,
                       float* __restrict__ out) {
    __shared__ float red[8];
    const int tid = threadIdx.x;
    float s = 0.f;
    for (int i = tid; i < N2; i += 512) {
        const int p = (i < NPAIR) ? i : i - NPAIR;
        s += INV_T + __logf(rowsum[i]) - pos[p];
    }
#pragma unroll
    for (int off = 32; off; off >>= 1) s += __shfl_xor(s, off);
    if ((tid & 63) == 0) red[tid >> 6] = s;
    __syncthreads();
    if (tid == 0) {
        float t = 0.f;
#pragma unroll
        for (int w = 0; w < 8; ++w) t += red[w];
        out[0] = t / (float)N2;
    }
}

extern "C" void kernel_launch(void* const* d_in, const int* in_sizes, int n_in,
                              void* d_out, int out_size, void* d_ws, size_t ws_size,
                              hipStream_t stream) {
    const float* z1 = (const float*)d_in[0];
    const float* z2 = (const float*)d_in[1];
    unsigned char* zq = (unsigned char*)d_ws;                         // 8192*768 fp8
    float* rowsum = (float*)((char*)d_ws + (size_t)N2 * DIM);         // 8192 f32
    float* pos = rowsum + N2;                                         // 4096 f32
    float* out = (float*)d_out;

    hipLaunchKernelGGL(knorm, dim3(N2 / 4), dim3(256), 0, stream, z1, z2, zq);
    hipLaunchKernelGGL(kpos, dim3(NPAIR / 4), dim3(256), 0, stream, zq, pos);
    hipMemsetAsync(rowsum, 0, N2 * sizeof(float), stream);
    hipLaunchKernelGGL(klse, dim3(NBI, NSTRIP), dim3(256), 0, stream, zq, rowsum);
    hipLaunchKernelGGL(kfinal, dim3(1), dim3(512), 0, stream, rowsum, pos, out);
}

// Round 14
// 131.084 us; speedup vs baseline: 1.9357x; 1.9357x over previous
//
#include <hip/hip_runtime.h>
#include <hip/hip_bf16.h>

#define NPAIR 4096
#define DIM   768            // fp8: 768 bytes per row
#define N2    8192
#define BM    128            // block rows (4 waves as 2x2, each 64x64)
#define BNB   128            // block cols per col-block
#define KBLK  64             // K tile bytes -> A,B tiles 8KB each; dbuf = 32KB
#define KITER (DIM / KBLK)   // 12
#define NSTRIP 16            // grid.y
#define CPB   ((N2 / BNB) / NSTRIP)    // 4 col-blocks per strip
#define NBI   (N2 / BM)      // 64
#define TOT   (CPB * KITER)  // 48 K-tile iterations per block

constexpr float INV_T = 1.0f / 0.07f;  // also the fixed softmax max M

typedef float f32x16 __attribute__((ext_vector_type(16)));
#define AS1 __attribute__((address_space(1)))
#define AS3 __attribute__((address_space(3)))

// ---------------- normalize: one wave per row, fp32 in -> fp8 e4m3 out ------
__global__ void knorm(const float* __restrict__ z1, const float* __restrict__ z2,
                      unsigned char* __restrict__ zq) {
    const int row  = blockIdx.x * 4 + (threadIdx.x >> 6);
    const int lane = threadIdx.x & 63;
    const float* src = (row < NPAIR) ? (z1 + (size_t)row * DIM)
                                     : (z2 + (size_t)(row - NPAIR) * DIM);
    float4 v[3];
    float ss = 0.f;
#pragma unroll
    for (int i = 0; i < 3; ++i) {
        v[i] = reinterpret_cast<const float4*>(src)[lane + 64 * i];
        ss += v[i].x * v[i].x + v[i].y * v[i].y + v[i].z * v[i].z + v[i].w * v[i].w;
    }
#pragma unroll
    for (int off = 32; off; off >>= 1) ss += __shfl_xor(ss, off);
    const float scale = 1.0f / fmaxf(sqrtf(ss), 1e-12f);
    unsigned int* dst = reinterpret_cast<unsigned int*>(zq + (size_t)row * DIM);
#pragma unroll
    for (int i = 0; i < 3; ++i) {
        unsigned int u = 0;
        u = __builtin_amdgcn_cvt_pk_fp8_f32(v[i].x * scale, v[i].y * scale, u, false);
        u = __builtin_amdgcn_cvt_pk_fp8_f32(v[i].z * scale, v[i].w * scale, u, true);
        dst[lane + 64 * i] = u;
    }
}

// ---------------- positive-pair dots from fp8 (consistent with klse) --------
__global__ void kpos(const unsigned char* __restrict__ zq, float* __restrict__ pos) {
    const int pair = blockIdx.x * 4 + (threadIdx.x >> 6);
    const int lane = threadIdx.x & 63;
    const unsigned int* a = reinterpret_cast<const unsigned int*>(zq + (size_t)pair * DIM);
    const unsigned int* b = reinterpret_cast<const unsigned int*>(zq + (size_t)(pair + NPAIR) * DIM);
    float s = 0.f;
#pragma unroll
    for (int i = 0; i < 3; ++i) {
        const unsigned int ua = a[lane + 64 * i];
        const unsigned int ub = b[lane + 64 * i];
        s += __builtin_amdgcn_cvt_f32_fp8(ua, 0) * __builtin_amdgcn_cvt_f32_fp8(ub, 0);
        s += __builtin_amdgcn_cvt_f32_fp8(ua, 1) * __builtin_amdgcn_cvt_f32_fp8(ub, 1);
        s += __builtin_amdgcn_cvt_f32_fp8(ua, 2) * __builtin_amdgcn_cvt_f32_fp8(ub, 2);
        s += __builtin_amdgcn_cvt_f32_fp8(ua, 3) * __builtin_amdgcn_cvt_f32_fp8(ub, 3);
    }
#pragma unroll
    for (int off = 32; off; off >>= 1) s += __shfl_xor(s, off);
    if (lane == 0) pos[pair] = s * INV_T;
}

// ---------------- main: R11 pipeline at 4 blocks/CU -------------------------
// 2-phase dbuf (stage next FIRST, one vmcnt(0)+barrier per iter), 32KB LDS,
// 4-way swizzle (slot = k ^ ((row>>1)&3)). Single change vs R11:
// __launch_bounds__(256,4) -> 128-reg budget (we use ~112 unified) ->
// 4 blocks/CU co-resident (LDS 4x32KB=128K <= 160K; grid 1024 = 4/CU exact).
__global__ __launch_bounds__(256, 4) void klse(const unsigned char* __restrict__ zq,
                                               float* __restrict__ rowsum) {
    __shared__ __align__(16) unsigned char As[2][BM * KBLK];   // 2 x 8 KB
    __shared__ __align__(16) unsigned char Bs[2][BM * KBLK];   // 2 x 8 KB
    const int tid  = threadIdx.x;
    const int wave = tid >> 6;
    const int lane = tid & 63;
    const int wr = wave >> 1, wc = wave & 1;
    const int hi = lane >> 5, rlo = lane & 31;
    const int bi = blockIdx.x;
    const int rb = bi * BM;

    const int sw  = (rlo >> 1) & 3;              // row-pair swizzle class
    const int raA = (wr * 64 + rlo) * KBLK;      // A sub 0 row base (bytes)
    const int raB = raA + 32 * KBLK;             // A sub 1
    const int caA = (wc * 64 + rlo) * KBLK;      // B sub 0 col base
    const int caB = caA + 32 * KBLK;             // B sub 1

    // stage K-tile (ct,kt) into buffer buf: 512 granules of 16B per matrix
    auto stage = [&](int ct, int kt, int buf) {
        const int c0 = (blockIdx.y * CPB + ct) * BNB;
        const int koff = kt * KBLK;
#pragma unroll
        for (int i = 0; i < 2; ++i) {
            const int g = i * 256 + tid;         // granule in [0,512)
            const int r = g >> 2, s = g & 3;
            const int ks = koff + ((s ^ ((r >> 1) & 3)) << 4);
            __builtin_amdgcn_global_load_lds(
                (const AS1 unsigned int*)(zq + (size_t)(rb + r) * DIM + ks),
                (AS3 unsigned int*)(&As[buf][g * 16]), 16, 0, 0);
            __builtin_amdgcn_global_load_lds(
                (const AS1 unsigned int*)(zq + (size_t)(c0 + r) * DIM + ks),
                (AS3 unsigned int*)(&Bs[buf][g * 16]), 16, 0, 0);
        }
    };

    f32x16 acc00 = {}, acc01 = {}, acc10 = {}, acc11 = {};

    stage(0, 0, 0);
    asm volatile("s_waitcnt vmcnt(0)" ::: "memory");
    __builtin_amdgcn_s_barrier();

    int ct = 0, kt = 0;
    for (int it = 0; it < TOT; ++it) {
        const int cur = it & 1;
        int nct = ct, nkt = kt + 1;
        if (nkt == KITER) { nkt = 0; ++nct; }
        if (it + 1 < TOT) stage(nct, nkt, cur ^ 1);   // issue next-tile loads FIRST

        // compute on buf[cur]: 4 K-steps x 2x2 subtiles
#pragma unroll
        for (int ts = 0; ts < 4; ++ts) {
            const int so = ((ts ^ sw) << 4) + (hi << 3);  // swizzled octet offset
            long a0 = *reinterpret_cast<const long*>(&As[cur][raA + so]);
            long a1 = *reinterpret_cast<const long*>(&As[cur][raB + so]);
            long b0 = *reinterpret_cast<const long*>(&Bs[cur][caA + so]);
            long b1 = *reinterpret_cast<const long*>(&Bs[cur][caB + so]);
            acc00 = __builtin_amdgcn_mfma_f32_32x32x16_fp8_fp8(a0, b0, acc00, 0, 0, 0);
            acc01 = __builtin_amdgcn_mfma_f32_32x32x16_fp8_fp8(a0, b1, acc01, 0, 0, 0);
            acc10 = __builtin_amdgcn_mfma_f32_32x32x16_fp8_fp8(a1, b0, acc10, 0, 0, 0);
            acc11 = __builtin_amdgcn_mfma_f32_32x32x16_fp8_fp8(a1, b1, acc11, 0, 0, 0);
        }

        asm volatile("s_waitcnt vmcnt(0)" ::: "memory");  // next buffer landed
        __builtin_amdgcn_s_barrier();                     // all reads of buf^1 done too

        if (kt == KITER - 1) {
            // ---------- epilogue for col-block ct: exp, mask, reduce --------
            const int cblk = blockIdx.y * CPB + ct;
            const bool on_diag = (cblk == bi);
            const int row0b = rb + wr * 64 + 4 * hi;
            const int colg  = cblk * BNB + wc * 64 + rlo;
            float ps0[16], ps1[16];
#pragma unroll
            for (int r = 0; r < 16; ++r) {
                const int rg0 = row0b + (r & 3) + 8 * (r >> 2);
                float e00 = __expf((acc00[r] - 1.0f) * INV_T);
                float e01 = __expf((acc01[r] - 1.0f) * INV_T);
                float e10 = __expf((acc10[r] - 1.0f) * INV_T);
                float e11 = __expf((acc11[r] - 1.0f) * INV_T);
                if (on_diag) {
                    if (rg0 == colg)           e00 = 0.f;
                    if (rg0 == colg + 32)      e01 = 0.f;
                    if (rg0 + 32 == colg)      e10 = 0.f;
                    if (rg0 + 32 == colg + 32) e11 = 0.f;
                }
                ps0[r] = e00 + e01;
                ps1[r] = e10 + e11;
            }
#pragma unroll
            for (int r = 0; r < 16; ++r) {
#pragma unroll
                for (int m = 1; m < 32; m <<= 1) {
                    ps0[r] += __shfl_xor(ps0[r], m);
                    ps1[r] += __shfl_xor(ps1[r], m);
                }
            }
            if (rlo == 0) {
#pragma unroll
                for (int r = 0; r < 16; ++r) {
                    const int rg0 = row0b + (r & 3) + 8 * (r >> 2);
                    atomicAdd(&rowsum[rg0], ps0[r]);
                    atomicAdd(&rowsum[rg0 + 32], ps1[r]);
                }
            }
            acc00 = f32x16{}; acc01 = f32x16{};
            acc10 = f32x16{}; acc11 = f32x16{};
        }
        ct = nct; kt = nkt;
    }
}

// ---------------- final: loss = mean(M + log S_i - pos) ---------------------
__global__ void kfinal(const float* __restrict__ rowsum, const float* __restrict__ pos,
                       float* __restrict__ out) {
    __shared__ float red[8];
    const int tid = threadIdx.x;
    float s = 0.f;
    for (int i = tid; i < N2; i += 512) {
        const int p = (i < NPAIR) ? i : i - NPAIR;
        s += INV_T + __logf(rowsum[i]) - pos[p];
    }
#pragma unroll
    for (int off = 32; off; off >>= 1) s += __shfl_xor(s, off);
    if ((tid & 63) == 0) red[tid >> 6] = s;
    __syncthreads();
    if (tid == 0) {
        float t = 0.f;
#pragma unroll
        for (int w = 0; w < 8; ++w) t += red[w];
        out[0] = t / (float)N2;
    }
}

extern "C" void kernel_launch(void* const* d_in, const int* in_sizes, int n_in,
                              void* d_out, int out_size, void* d_ws, size_t ws_size,
                              hipStream_t stream) {
    const float* z1 = (const float*)d_in[0];
    const float* z2 = (const float*)d_in[1];
    unsigned char* zq = (unsigned char*)d_ws;                         // 8192*768 fp8
    float* rowsum = (float*)((char*)d_ws + (size_t)N2 * DIM);         // 8192 f32
    float* pos = rowsum + N2;                                         // 4096 f32
    float* out = (float*)d_out;

    hipLaunchKernelGGL(knorm, dim3(N2 / 4), dim3(256), 0, stream, z1, z2, zq);
    hipLaunchKernelGGL(kpos, dim3(NPAIR / 4), dim3(256), 0, stream, zq, pos);
    hipMemsetAsync(rowsum, 0, N2 * sizeof(float), stream);
    hipLaunchKernelGGL(klse, dim3(NBI, NSTRIP), dim3(256), 0, stream, zq, rowsum);
    hipLaunchKernelGGL(kfinal, dim3(1), dim3(512), 0, stream, rowsum, pos, out);
}